// Round 9
// baseline (217.655 us; speedup 1.0000x reference)
//
#include <hip/hip_runtime.h>
#include <math.h>

typedef __attribute__((ext_vector_type(8)))  short bf16x8;   // 8 bf16 = 4 VGPRs
typedef __attribute__((ext_vector_type(16))) float f32x16;   // 32x32 MFMA acc

#define NEXP 8
#define BATCH 2048

__device__ __forceinline__ unsigned short f2bf(float f) {
    union { float f; unsigned u; } v; v.f = f;
    unsigned r = v.u + 0x7FFFu + ((v.u >> 16) & 1u);   // RTNE
    return (unsigned short)(r >> 16);
}

// ---------------------------------------------------------------------------
// Pack f32 W/x -> bf16 32x32x16-MFMA fragment tiles (1 KB contiguous each).
// B tile (32n x 16k), lin = (nb*KBw + kb)*8 + e:
//   lane l, j: W[e][nb*32 + (l&31)][kb*16 + (l>>5)*8 + j]
// A tile (32m x 16k), lin = mb*KB0 + kb:
//   lane l, j: x[mb*32 + (l&31)][kb*16 + (l>>5)*8 + j]
// Block covers 32 rows x 256 cols of one array. Grid 2176:
//   [0,512) W0 (nb32 x kc2 x e8), [512,1536) W1 (32x4x8),
//   [1536,2048) W2 (16x4x8), [2048,2176) x (mb64 x kc2)
// ---------------------------------------------------------------------------
__global__ __launch_bounds__(256) void pack32(
    const float* __restrict__ W0, const float* __restrict__ W1,
    const float* __restrict__ W2, const float* __restrict__ x,
    unsigned short* __restrict__ W0p, unsigned short* __restrict__ W1p,
    unsigned short* __restrict__ W2p, unsigned short* __restrict__ x0p)
{
    __shared__ float T[32 * 260];
    const int bid = blockIdx.x, tid = threadIdx.x;

    const float* src; unsigned short* out;
    int Din, rowbase, kc, KBw, lin_nb_e_base; bool isx = false;
    if (bid < 512) {            // W0: Din 512, Dout 1024, KBw 32
        int c = bid;            const int e = c & 7, kcl = (c >> 3) & 1, nb = c >> 4;
        src = W0; out = W0p; Din = 512; KBw = 32; kc = kcl;
        rowbase = e * 1024 + nb * 32; lin_nb_e_base = (nb * KBw) * 8 + e;
    } else if (bid < 1536) {    // W1: Din 1024, Dout 1024, KBw 64
        int c = bid - 512;      const int e = c & 7, kcl = (c >> 3) & 3, nb = c >> 5;
        src = W1; out = W1p; Din = 1024; KBw = 64; kc = kcl;
        rowbase = e * 1024 + nb * 32; lin_nb_e_base = (nb * KBw) * 8 + e;
    } else if (bid < 2048) {    // W2: Din 1024, Dout 512, KBw 64
        int c = bid - 1536;     const int e = c & 7, kcl = (c >> 3) & 3, nb = c >> 5;
        src = W2; out = W2p; Din = 1024; KBw = 64; kc = kcl;
        rowbase = e * 512 + nb * 32; lin_nb_e_base = (nb * KBw) * 8 + e;
    } else {                    // x: Din 512, KB0 32
        int c = bid - 2048;     const int kcl = c & 1, mb = c >> 1;
        src = x; out = x0p; Din = 512; KBw = 32; kc = kcl;
        rowbase = mb * 32; lin_nb_e_base = mb * 32; isx = true;
    }

    #pragma unroll
    for (int it = 0; it < 8; ++it) {            // 32 rows x 64 float4
        const int idx = tid + 256 * it;
        const int row = idx >> 6, c4 = idx & 63;
        float4 v = *(const float4*)(src + (size_t)(rowbase + row) * Din + kc * 256 + c4 * 4);
        *(float4*)(T + row * 260 + c4 * 4) = v;
    }
    __syncthreads();
    #pragma unroll
    for (int it = 0; it < 4; ++it) {            // 16 frags x 64 lanes
        const int s = tid + 256 * it;
        const int f = s >> 6, l = s & 63;
        const float* p = T + (l & 31) * 260 + f * 16 + (l >> 5) * 8;
        bf16x8 h;
        #pragma unroll
        for (int j = 0; j < 8; ++j) h[j] = (short)f2bf(p[j]);
        const int lin = isx ? (lin_nb_e_base + kc * 16 + f)
                            : (lin_nb_e_base + (kc * 16 + f) * 8);
        *(bf16x8*)(out + (size_t)lin * 512 + l * 8) = h;
    }
}

// ---------------------------------------------------------------------------
// Blended-expert layer, 32x32x16 bf16 MFMA, packed operands, no LDS/barriers
// in the K-loop. 256 threads = 4 waves; wave ew owns experts {2ew,2ew+1}
// over the FULL 64m x 64n tile: per K=16 step loads 2 A + 4 B frags (6 KB)
// for 8 MFMA (42.7 FLOP/B -- 1.33-2x less L1 traffic/FLOP than R8).
// acc = 2t x 2u x 2e f32x16 = 128 VGPR; frags double-buffered.
// Epilogue: 2-buf 2-phase cross-wave blend reduce (35 KB LDS), bias+ELU;
// output packed (next layer A-frags) or f32 row-major. kk0/addbias allow
// K-splitting the last layer across two dispatches (partials summed by
// reduce2).
// ---------------------------------------------------------------------------
__global__ __launch_bounds__(256, 2) void moe_gemm32(
    const unsigned short* __restrict__ Xp,   // packed A frags (KBx tiles/mb)
    const unsigned short* __restrict__ Wp,   // packed B frags (KBx tiles/nb)
    const float* __restrict__ Bias,          // [NEXP, Dout]
    const float* __restrict__ WBl,           // [BATCH, NEXP]
    void* __restrict__ Yout,                 // packed bf16 or f32 row-major
    int KB, int kk0, int Dout, int KBx, int KBn, int act,
    int addbias, int packed_out)
{
    __shared__ __align__(16) float lds_f[2 * 64 * 68];    // ~34.8 KB

    const int tid = threadIdx.x;
    const int ew  = tid >> 6;                 // wave: e-pair {2ew, 2ew+1}
    const int l   = tid & 63;
    const int ln  = l & 31;                   // frag row/col lane
    const int lk  = l >> 5;                   // frag k-half
    const int e0  = 2 * ew;
    const int bx  = blockIdx.x;               // n0 = bx*64
    const int by  = blockIdx.y;               // m0 = by*64
    const int m0  = by * 64;
    const int n0  = bx * 64;

    f32x16 acc[2][2][2];                      // [e][t][u]
    #pragma unroll
    for (int e = 0; e < 2; ++e)
        #pragma unroll
        for (int t = 0; t < 2; ++t)
            #pragma unroll
            for (int u = 0; u < 2; ++u)
                #pragma unroll
                for (int i = 0; i < 16; ++i) acc[e][t][u][i] = 0.f;

    // packed byte offsets at k-step kk0
    unsigned aoff[2], boff[2][2];             // [t], [e][u]
    #pragma unroll
    for (int t = 0; t < 2; ++t)
        aoff[t] = ((unsigned)(by * 2 + t) * KBx + kk0) * 1024u + l * 16u;
    #pragma unroll
    for (int u = 0; u < 2; ++u)
        #pragma unroll
        for (int e = 0; e < 2; ++e)
            boff[e][u] = (((unsigned)(bx * 2 + u) * KBx + kk0) * 8 + e0 + e) * 1024u + l * 16u;
    const char* xc = (const char*)Xp;
    const char* wc = (const char*)Wp;

    bf16x8 aR[2][2], bR[2][2][2];             // [buf][t], [buf][e][u]

    auto LOAD = [&](int s, int kk) {
        const unsigned ab = (unsigned)kk * 1024u;
        const unsigned bb = (unsigned)kk * 8192u;
        #pragma unroll
        for (int t = 0; t < 2; ++t)
            aR[s][t] = *(const bf16x8*)(xc + aoff[t] + ab);
        #pragma unroll
        for (int e = 0; e < 2; ++e)
            #pragma unroll
            for (int u = 0; u < 2; ++u)
                bR[s][e][u] = *(const bf16x8*)(wc + boff[e][u] + bb);
    };
    auto MF = [&](int s) {
        #pragma unroll
        for (int e = 0; e < 2; ++e)
            #pragma unroll
            for (int u = 0; u < 2; ++u)
                #pragma unroll
                for (int t = 0; t < 2; ++t)
                    acc[e][t][u] = __builtin_amdgcn_mfma_f32_32x32x16_bf16(
                        aR[s][t], bR[s][e][u], acc[e][t][u], 0, 0, 0);
    };

    LOAD(0, 0);
    for (int kk = 0; kk < KB; kk += 2) {      // KB even
        if (kk + 1 < KB) LOAD(1, kk + 1);
        MF(0);
        if (kk + 2 < KB) LOAD(0, kk + 2);
        MF(1);
    }

    // ---- epilogue ----
    float bi[2][2];                           // [e][u]
    #pragma unroll
    for (int e = 0; e < 2; ++e)
        #pragma unroll
        for (int u = 0; u < 2; ++u)
            bi[e][u] = addbias ? Bias[(size_t)(e0 + e) * Dout + n0 + u * 32 + ln] : 0.f;

    float* pb = lds_f + (ew & 1) * (64 * 68);

    // C/D 32x32 layout: reg r -> row (r&3)+8*(r>>2)+4*lk, col ln (m74/m101)
    if (ew < 2) {
        #pragma unroll
        for (int t = 0; t < 2; ++t)
            #pragma unroll
            for (int r = 0; r < 16; ++r) {
                const int row = t * 32 + (r & 3) + 8 * (r >> 2) + 4 * lk;
                float2 wbp = ((const float2*)(WBl + (size_t)(m0 + row) * NEXP))[ew];
                #pragma unroll
                for (int u = 0; u < 2; ++u)
                    pb[row * 68 + u * 32 + ln] =
                        wbp.x * (acc[0][t][u][r] + bi[0][u]) + wbp.y * (acc[1][t][u][r] + bi[1][u]);
            }
    }
    __syncthreads();
    if (ew >= 2) {
        #pragma unroll
        for (int t = 0; t < 2; ++t)
            #pragma unroll
            for (int r = 0; r < 16; ++r) {
                const int row = t * 32 + (r & 3) + 8 * (r >> 2) + 4 * lk;
                float2 wbp = ((const float2*)(WBl + (size_t)(m0 + row) * NEXP))[ew];
                #pragma unroll
                for (int u = 0; u < 2; ++u)
                    pb[row * 68 + u * 32 + ln] +=
                        wbp.x * (acc[0][t][u][r] + bi[0][u]) + wbp.y * (acc[1][t][u][r] + bi[1][u]);
            }
    }
    __syncthreads();

    float* pb0 = lds_f;
    float* pb1 = lds_f + 64 * 68;
    if (packed_out) {
        // 8 next-layer A-frags (2 m-halves x 4 k-tiles), 16B per slot
        #pragma unroll
        for (int it = 0; it < 2; ++it) {
            const int s = tid + 256 * it;
            const int f = s >> 6, l2 = s & 63;
            const int row = (f & 1) * 32 + (l2 & 31);
            const int cb  = (f >> 1) * 16 + (l2 >> 5) * 8;
            bf16x8 h;
            #pragma unroll
            for (int j = 0; j < 8; ++j) {
                float v = pb0[row * 68 + cb + j] + pb1[row * 68 + cb + j];
                if (act) v = v > 0.f ? v : expm1f(v);
                h[j] = (short)f2bf(v);
            }
            const unsigned lin = (unsigned)(by * 2 + (f & 1)) * KBn + bx * 4 + (f >> 1);
            *(bf16x8*)((unsigned short*)Yout + (size_t)lin * 512 + l2 * 8) = h;
        }
    } else {
        #pragma unroll
        for (int it = 0; it < 4; ++it) {
            const int s = tid + 256 * it;               // 1024 float4 slots
            const int row = s >> 4, c4 = (s & 15) * 4;
            float4 a = *(const float4*)(pb0 + row * 68 + c4);
            float4 b = *(const float4*)(pb1 + row * 68 + c4);
            a.x += b.x; a.y += b.y; a.z += b.z; a.w += b.w;
            if (act) {
                a.x = a.x > 0.f ? a.x : expm1f(a.x);
                a.y = a.y > 0.f ? a.y : expm1f(a.y);
                a.z = a.z > 0.f ? a.z : expm1f(a.z);
                a.w = a.w > 0.f ? a.w : expm1f(a.w);
            }
            *(float4*)((float*)Yout + (size_t)(m0 + row) * Dout + n0 + c4) = a;
        }
    }
}

__global__ __launch_bounds__(256) void reduce2(
    const float* __restrict__ p0, const float* __restrict__ p1,
    float* __restrict__ out, int n4)
{
    int i = blockIdx.x * blockDim.x + threadIdx.x;
    if (i >= n4) return;
    float4 a = ((const float4*)p0)[i];
    float4 b = ((const float4*)p1)[i];
    a.x += b.x; a.y += b.y; a.z += b.z; a.w += b.w;
    ((float4*)out)[i] = a;
}

// ---------------- fp32 fallback for small ws_size ----------------
#define BM 64
#define BNF 64
#define BKF 16
#define PAD 4

__global__ __launch_bounds__(256) void moe_layer_f32(
    const float* __restrict__ X, const float* __restrict__ W,
    const float* __restrict__ Bias, const float* __restrict__ WB,
    float* __restrict__ Y, int Din, int Dout, int act)
{
    __shared__ float As[BKF][BM + PAD];
    __shared__ float Bs[BKF][BNF + PAD];
    const int tid = threadIdx.x;
    const int tm = tid >> 4, tn = tid & 15;
    const int m0 = blockIdx.y * BM, n0 = blockIdx.x * BNF;
    const int lr = tid >> 2, lc = (tid & 3) << 2;
    float acc[4][4] = {};
    const float* xrow  = X  + (size_t)(m0 + lr) * Din;
    const float* wbrow = WB + (size_t)(m0 + lr) * NEXP;
    const float* wrow0 = W  + (size_t)(n0 + lr) * Din;
    for (int e = 0; e < NEXP; ++e) {
        const float wbe = wbrow[e];
        const float* wrow = wrow0 + (size_t)e * Dout * Din;
        for (int k0 = 0; k0 < Din; k0 += BKF) {
            float4 av = *(const float4*)(xrow + k0 + lc);
            float4 bv = *(const float4*)(wrow + k0 + lc);
            __syncthreads();
            As[lc+0][lr] = av.x*wbe; As[lc+1][lr] = av.y*wbe;
            As[lc+2][lr] = av.z*wbe; As[lc+3][lr] = av.w*wbe;
            Bs[lc+0][lr] = bv.x; Bs[lc+1][lr] = bv.y;
            Bs[lc+2][lr] = bv.z; Bs[lc+3][lr] = bv.w;
            __syncthreads();
            #pragma unroll
            for (int k = 0; k < BKF; ++k) {
                float4 a = *(const float4*)&As[k][tm << 2];
                float4 b = *(const float4*)&Bs[k][tn << 2];
                acc[0][0]+=a.x*b.x; acc[0][1]+=a.x*b.y; acc[0][2]+=a.x*b.z; acc[0][3]+=a.x*b.w;
                acc[1][0]+=a.y*b.x; acc[1][1]+=a.y*b.y; acc[1][2]+=a.y*b.z; acc[1][3]+=a.y*b.w;
                acc[2][0]+=a.z*b.x; acc[2][1]+=a.z*b.y; acc[2][2]+=a.z*b.z; acc[2][3]+=a.z*b.w;
                acc[3][0]+=a.w*b.x; acc[3][1]+=a.w*b.y; acc[3][2]+=a.w*b.z; acc[3][3]+=a.w*b.w;
            }
        }
    }
    #pragma unroll
    for (int im = 0; im < 4; ++im) {
        const int m = m0 + (tm << 2) + im;
        const float* wbm = WB + (size_t)m * NEXP;
        float wv[NEXP];
        #pragma unroll
        for (int e = 0; e < NEXP; ++e) wv[e] = wbm[e];
        #pragma unroll
        for (int in = 0; in < 4; ++in) {
            const int n = n0 + (tn << 2) + in;
            float bsum = 0.f;
            #pragma unroll
            for (int e = 0; e < NEXP; ++e) bsum += wv[e] * Bias[(size_t)e * Dout + n];
            float v = acc[im][in] + bsum;
            if (act) v = v > 0.f ? v : expm1f(v);
            acc[im][in] = v;
        }
        float4 o = make_float4(acc[im][0], acc[im][1], acc[im][2], acc[im][3]);
        *(float4*)(Y + (size_t)m * Dout + n0 + (tn << 2)) = o;
    }
}

extern "C" void kernel_launch(void* const* d_in, const int* in_sizes, int n_in,
                              void* d_out, int out_size, void* d_ws, size_t ws_size,
                              hipStream_t stream)
{
    (void)in_sizes; (void)n_in; (void)out_size;
    const float* wb = (const float*)d_in[0];
    const float* x  = (const float*)d_in[1];
    const float* W0 = (const float*)d_in[2];
    const float* B0 = (const float*)d_in[3];
    const float* W1 = (const float*)d_in[4];
    const float* B1 = (const float*)d_in[5];
    const float* W2 = (const float*)d_in[6];
    const float* B2 = (const float*)d_in[7];
    float* out = (float*)d_out;

    const size_t NW0 = (size_t)8*1024*512, NW1 = (size_t)8*1024*1024, NW2 = (size_t)8*512*1024;
    const size_t NX0 = (size_t)BATCH*512, NX1 = (size_t)BATCH*1024;
    const size_t need_main  = (NW0 + NW1 + NW2 + NX0 + 2 * NX1) * 2;          // ~44 MB
    const size_t need_split = need_main + 2 * (size_t)BATCH * 512 * 4;        // +8 MB

    if (ws_size >= need_main) {
        unsigned short* W0p = (unsigned short*)d_ws;
        unsigned short* W1p = W0p + NW0;
        unsigned short* W2p = W1p + NW1;
        unsigned short* x0p = W2p + NW2;
        unsigned short* x1p = x0p + NX0;
        unsigned short* x2p = x1p + NX1;
        pack32<<<2176, 256, 0, stream>>>(W0, W1, W2, x, W0p, W1p, W2p, x0p);
        // L0: K=512 (KBx=32), Dout=1024, ELU, packed out (next KBx=64)
        moe_gemm32<<<dim3(16, 32), 256, 0, stream>>>(x0p, W0p, B0, wb, x1p,
                                                     32, 0, 1024, 32, 64, 1, 1, 1);
        // L1: K=1024 (KBx=64), Dout=1024, ELU, packed out (next KBx=64)
        moe_gemm32<<<dim3(16, 32), 256, 0, stream>>>(x1p, W1p, B1, wb, x2p,
                                                     64, 0, 1024, 64, 64, 1, 1, 1);
        if (ws_size >= need_split) {
            float* p0 = (float*)(x2p + NX1);
            float* p1 = p0 + (size_t)BATCH * 512;
            moe_gemm32<<<dim3(8, 32), 256, 0, stream>>>(x2p, W2p, B2, wb, p0,
                                                        32, 0, 512, 64, 0, 0, 1, 0);
            moe_gemm32<<<dim3(8, 32), 256, 0, stream>>>(x2p, W2p, B2, wb, p1,
                                                        32, 32, 512, 64, 0, 0, 0, 0);
            reduce2<<<1024, 256, 0, stream>>>(p0, p1, out, BATCH * 512 / 4);
        } else {
            moe_gemm32<<<dim3(8, 32), 256, 0, stream>>>(x2p, W2p, B2, wb, out,
                                                        64, 0, 512, 64, 0, 0, 1, 0);
        }
    } else {
        float* x1 = (float*)d_ws;
        float* x2 = x1 + (size_t)BATCH * 1024;
        moe_layer_f32<<<dim3(1024/BNF, BATCH/BM), 256, 0, stream>>>(x,  W0, B0, wb, x1, 512,  1024, 1);
        moe_layer_f32<<<dim3(1024/BNF, BATCH/BM), 256, 0, stream>>>(x1, W1, B1, wb, x2, 1024, 1024, 1);
        moe_layer_f32<<<dim3(512/BNF,  BATCH/BM), 256, 0, stream>>>(x2, W2, B2, wb, out, 1024, 512,  0);
    }
}

// Round 10
// 214.493 us; speedup vs baseline: 1.0147x; 1.0147x over previous
//
#include <hip/hip_runtime.h>
#include <math.h>

typedef __attribute__((ext_vector_type(8)))  short bf16x8;   // 8 bf16 = 4 VGPRs
typedef __attribute__((ext_vector_type(16))) float f32x16;   // 32x32 MFMA acc

#define NEXP 8
#define BATCH 2048

__device__ __forceinline__ unsigned short f2bf(float f) {
    union { float f; unsigned u; } v; v.f = f;
    unsigned r = v.u + 0x7FFFu + ((v.u >> 16) & 1u);   // RTNE
    return (unsigned short)(r >> 16);
}

// ---------------------------------------------------------------------------
// Pack f32 W/x -> bf16 32x32x16-MFMA fragment tiles (1 KB contiguous each).
// (unchanged from R9)
// ---------------------------------------------------------------------------
__global__ __launch_bounds__(256) void pack32(
    const float* __restrict__ W0, const float* __restrict__ W1,
    const float* __restrict__ W2, const float* __restrict__ x,
    unsigned short* __restrict__ W0p, unsigned short* __restrict__ W1p,
    unsigned short* __restrict__ W2p, unsigned short* __restrict__ x0p)
{
    __shared__ float T[32 * 260];
    const int bid = blockIdx.x, tid = threadIdx.x;

    const float* src; unsigned short* out;
    int Din, rowbase, kc, KBw, lin_nb_e_base; bool isx = false;
    if (bid < 512) {            // W0: Din 512, Dout 1024, KBw 32
        int c = bid;            const int e = c & 7, kcl = (c >> 3) & 1, nb = c >> 4;
        src = W0; out = W0p; Din = 512; KBw = 32; kc = kcl;
        rowbase = e * 1024 + nb * 32; lin_nb_e_base = (nb * KBw) * 8 + e;
    } else if (bid < 1536) {    // W1: Din 1024, Dout 1024, KBw 64
        int c = bid - 512;      const int e = c & 7, kcl = (c >> 3) & 3, nb = c >> 5;
        src = W1; out = W1p; Din = 1024; KBw = 64; kc = kcl;
        rowbase = e * 1024 + nb * 32; lin_nb_e_base = (nb * KBw) * 8 + e;
    } else if (bid < 2048) {    // W2: Din 1024, Dout 512, KBw 64
        int c = bid - 1536;     const int e = c & 7, kcl = (c >> 3) & 3, nb = c >> 5;
        src = W2; out = W2p; Din = 1024; KBw = 64; kc = kcl;
        rowbase = e * 512 + nb * 32; lin_nb_e_base = (nb * KBw) * 8 + e;
    } else {                    // x: Din 512, KB0 32
        int c = bid - 2048;     const int kcl = c & 1, mb = c >> 1;
        src = x; out = x0p; Din = 512; KBw = 32; kc = kcl;
        rowbase = mb * 32; lin_nb_e_base = mb * 32; isx = true;
    }

    #pragma unroll
    for (int it = 0; it < 8; ++it) {            // 32 rows x 64 float4
        const int idx = tid + 256 * it;
        const int row = idx >> 6, c4 = idx & 63;
        float4 v = *(const float4*)(src + (size_t)(rowbase + row) * Din + kc * 256 + c4 * 4);
        *(float4*)(T + row * 260 + c4 * 4) = v;
    }
    __syncthreads();
    #pragma unroll
    for (int it = 0; it < 4; ++it) {            // 16 frags x 64 lanes
        const int s = tid + 256 * it;
        const int f = s >> 6, l = s & 63;
        const float* p = T + (l & 31) * 260 + f * 16 + (l >> 5) * 8;
        bf16x8 h;
        #pragma unroll
        for (int j = 0; j < 8; ++j) h[j] = (short)f2bf(p[j]);
        const int lin = isx ? (lin_nb_e_base + kc * 16 + f)
                            : (lin_nb_e_base + (kc * 16 + f) * 8);
        *(bf16x8*)(out + (size_t)lin * 512 + l * 8) = h;
    }
}

// ---------------------------------------------------------------------------
// Blended-expert layer, 32x32x16 bf16 MFMA, packed operands.
// R10 change vs R9: DEPTH-4 register software pipeline. Per wave-step a
// load must cover ~700-1000 cyc of under-load L2/L3 latency but one step
// only holds 8 MFMA = ~256 cyc of matrix-pipe work; depth-1 prefetch
// (R2..R9) therefore stalls ~700 cyc/step = the measured 26% MfmaUtil.
// With 4 steps in flight (24 outstanding 1KB loads/wave) the waitcnt for
// step k lands >= 3 wall-steps after issue -> latency covered; new ceiling
// is L1 delivery (~64 B/cyc vs 96 demanded) => ~55-65% duty expected.
// Buffers 96 VGPR + acc 128 (unified AGPR) ~ 240/wave, 2 waves/SIMD.
// ---------------------------------------------------------------------------
__global__ __launch_bounds__(256, 2) void moe_gemm32(
    const unsigned short* __restrict__ Xp,   // packed A frags (KBx tiles/mb)
    const unsigned short* __restrict__ Wp,   // packed B frags (KBx tiles/nb)
    const float* __restrict__ Bias,          // [NEXP, Dout]
    const float* __restrict__ WBl,           // [BATCH, NEXP]
    void* __restrict__ Yout,                 // packed bf16 or f32 row-major
    int KB, int kk0, int Dout, int KBx, int KBn, int act,
    int addbias, int packed_out)
{
    __shared__ __align__(16) float lds_f[2 * 64 * 68];    // ~34.8 KB

    const int tid = threadIdx.x;
    const int ew  = tid >> 6;                 // wave: e-pair {2ew, 2ew+1}
    const int l   = tid & 63;
    const int ln  = l & 31;                   // frag row/col lane
    const int lk  = l >> 5;                   // frag k-half
    const int e0  = 2 * ew;
    const int bx  = blockIdx.x;               // n0 = bx*64
    const int by  = blockIdx.y;               // m0 = by*64
    const int m0  = by * 64;
    const int n0  = bx * 64;

    f32x16 acc[2][2][2];                      // [e][t][u]
    #pragma unroll
    for (int e = 0; e < 2; ++e)
        #pragma unroll
        for (int t = 0; t < 2; ++t)
            #pragma unroll
            for (int u = 0; u < 2; ++u)
                #pragma unroll
                for (int i = 0; i < 16; ++i) acc[e][t][u][i] = 0.f;

    // packed byte offsets at k-step kk0
    unsigned aoff[2], boff[2][2];             // [t], [e][u]
    #pragma unroll
    for (int t = 0; t < 2; ++t)
        aoff[t] = ((unsigned)(by * 2 + t) * KBx + kk0) * 1024u + l * 16u;
    #pragma unroll
    for (int u = 0; u < 2; ++u)
        #pragma unroll
        for (int e = 0; e < 2; ++e)
            boff[e][u] = (((unsigned)(bx * 2 + u) * KBx + kk0) * 8 + e0 + e) * 1024u + l * 16u;
    const char* xc = (const char*)Xp;
    const char* wc = (const char*)Wp;

    bf16x8 aR[4][2], bR[4][2][2];             // depth-4 circular buffers

    auto LOAD = [&](int s, int kk) {
        const unsigned ab = (unsigned)kk * 1024u;
        const unsigned bb = (unsigned)kk * 8192u;
        #pragma unroll
        for (int t = 0; t < 2; ++t)
            aR[s][t] = *(const bf16x8*)(xc + aoff[t] + ab);
        #pragma unroll
        for (int e = 0; e < 2; ++e)
            #pragma unroll
            for (int u = 0; u < 2; ++u)
                bR[s][e][u] = *(const bf16x8*)(wc + boff[e][u] + bb);
    };
    auto MF = [&](int s) {
        #pragma unroll
        for (int e = 0; e < 2; ++e)
            #pragma unroll
            for (int u = 0; u < 2; ++u)
                #pragma unroll
                for (int t = 0; t < 2; ++t)
                    acc[e][t][u] = __builtin_amdgcn_mfma_f32_32x32x16_bf16(
                        aR[s][t], bR[s][e][u], acc[e][t][u], 0, 0, 0);
    };

    // prologue: 4 steps in flight (KB is 32 or 64, always >= 8, mult of 4)
    LOAD(0, 0); LOAD(1, 1); LOAD(2, 2); LOAD(3, 3);
    for (int kk = 0; kk < KB; kk += 4) {
        MF(0); if (kk + 4 < KB) LOAD(0, kk + 4);
        MF(1); if (kk + 5 < KB) LOAD(1, kk + 5);
        MF(2); if (kk + 6 < KB) LOAD(2, kk + 6);
        MF(3); if (kk + 7 < KB) LOAD(3, kk + 7);
    }

    // ---- epilogue (unchanged) ----
    float bi[2][2];                           // [e][u]
    #pragma unroll
    for (int e = 0; e < 2; ++e)
        #pragma unroll
        for (int u = 0; u < 2; ++u)
            bi[e][u] = addbias ? Bias[(size_t)(e0 + e) * Dout + n0 + u * 32 + ln] : 0.f;

    float* pb = lds_f + (ew & 1) * (64 * 68);

    // C/D 32x32 layout: reg r -> row (r&3)+8*(r>>2)+4*lk, col ln (m74/m101)
    if (ew < 2) {
        #pragma unroll
        for (int t = 0; t < 2; ++t)
            #pragma unroll
            for (int r = 0; r < 16; ++r) {
                const int row = t * 32 + (r & 3) + 8 * (r >> 2) + 4 * lk;
                float2 wbp = ((const float2*)(WBl + (size_t)(m0 + row) * NEXP))[ew];
                #pragma unroll
                for (int u = 0; u < 2; ++u)
                    pb[row * 68 + u * 32 + ln] =
                        wbp.x * (acc[0][t][u][r] + bi[0][u]) + wbp.y * (acc[1][t][u][r] + bi[1][u]);
            }
    }
    __syncthreads();
    if (ew >= 2) {
        #pragma unroll
        for (int t = 0; t < 2; ++t)
            #pragma unroll
            for (int r = 0; r < 16; ++r) {
                const int row = t * 32 + (r & 3) + 8 * (r >> 2) + 4 * lk;
                float2 wbp = ((const float2*)(WBl + (size_t)(m0 + row) * NEXP))[ew];
                #pragma unroll
                for (int u = 0; u < 2; ++u)
                    pb[row * 68 + u * 32 + ln] +=
                        wbp.x * (acc[0][t][u][r] + bi[0][u]) + wbp.y * (acc[1][t][u][r] + bi[1][u]);
            }
    }
    __syncthreads();

    float* pb0 = lds_f;
    float* pb1 = lds_f + 64 * 68;
    if (packed_out) {
        // 8 next-layer A-frags (2 m-halves x 4 k-tiles), 16B per slot
        #pragma unroll
        for (int it = 0; it < 2; ++it) {
            const int s = tid + 256 * it;
            const int f = s >> 6, l2 = s & 63;
            const int row = (f & 1) * 32 + (l2 & 31);
            const int cb  = (f >> 1) * 16 + (l2 >> 5) * 8;
            bf16x8 h;
            #pragma unroll
            for (int j = 0; j < 8; ++j) {
                float v = pb0[row * 68 + cb + j] + pb1[row * 68 + cb + j];
                if (act) v = v > 0.f ? v : expm1f(v);
                h[j] = (short)f2bf(v);
            }
            const unsigned lin = (unsigned)(by * 2 + (f & 1)) * KBn + bx * 4 + (f >> 1);
            *(bf16x8*)((unsigned short*)Yout + (size_t)lin * 512 + l2 * 8) = h;
        }
    } else {
        #pragma unroll
        for (int it = 0; it < 4; ++it) {
            const int s = tid + 256 * it;               // 1024 float4 slots
            const int row = s >> 4, c4 = (s & 15) * 4;
            float4 a = *(const float4*)(pb0 + row * 68 + c4);
            float4 b = *(const float4*)(pb1 + row * 68 + c4);
            a.x += b.x; a.y += b.y; a.z += b.z; a.w += b.w;
            if (act) {
                a.x = a.x > 0.f ? a.x : expm1f(a.x);
                a.y = a.y > 0.f ? a.y : expm1f(a.y);
                a.z = a.z > 0.f ? a.z : expm1f(a.z);
                a.w = a.w > 0.f ? a.w : expm1f(a.w);
            }
            *(float4*)((float*)Yout + (size_t)(m0 + row) * Dout + n0 + c4) = a;
        }
    }
}

__global__ __launch_bounds__(256) void reduce2(
    const float* __restrict__ p0, const float* __restrict__ p1,
    float* __restrict__ out, int n4)
{
    int i = blockIdx.x * blockDim.x + threadIdx.x;
    if (i >= n4) return;
    float4 a = ((const float4*)p0)[i];
    float4 b = ((const float4*)p1)[i];
    a.x += b.x; a.y += b.y; a.z += b.z; a.w += b.w;
    ((float4*)out)[i] = a;
}

// ---------------- fp32 fallback for small ws_size ----------------
#define BM 64
#define BNF 64
#define BKF 16
#define PAD 4

__global__ __launch_bounds__(256) void moe_layer_f32(
    const float* __restrict__ X, const float* __restrict__ W,
    const float* __restrict__ Bias, const float* __restrict__ WB,
    float* __restrict__ Y, int Din, int Dout, int act)
{
    __shared__ float As[BKF][BM + PAD];
    __shared__ float Bs[BKF][BNF + PAD];
    const int tid = threadIdx.x;
    const int tm = tid >> 4, tn = tid & 15;
    const int m0 = blockIdx.y * BM, n0 = blockIdx.x * BNF;
    const int lr = tid >> 2, lc = (tid & 3) << 2;
    float acc[4][4] = {};
    const float* xrow  = X  + (size_t)(m0 + lr) * Din;
    const float* wbrow = WB + (size_t)(m0 + lr) * NEXP;
    const float* wrow0 = W  + (size_t)(n0 + lr) * Din;
    for (int e = 0; e < NEXP; ++e) {
        const float wbe = wbrow[e];
        const float* wrow = wrow0 + (size_t)e * Dout * Din;
        for (int k0 = 0; k0 < Din; k0 += BKF) {
            float4 av = *(const float4*)(xrow + k0 + lc);
            float4 bv = *(const float4*)(wrow + k0 + lc);
            __syncthreads();
            As[lc+0][lr] = av.x*wbe; As[lc+1][lr] = av.y*wbe;
            As[lc+2][lr] = av.z*wbe; As[lc+3][lr] = av.w*wbe;
            Bs[lc+0][lr] = bv.x; Bs[lc+1][lr] = bv.y;
            Bs[lc+2][lr] = bv.z; Bs[lc+3][lr] = bv.w;
            __syncthreads();
            #pragma unroll
            for (int k = 0; k < BKF; ++k) {
                float4 a = *(const float4*)&As[k][tm << 2];
                float4 b = *(const float4*)&Bs[k][tn << 2];
                acc[0][0]+=a.x*b.x; acc[0][1]+=a.x*b.y; acc[0][2]+=a.x*b.z; acc[0][3]+=a.x*b.w;
                acc[1][0]+=a.y*b.x; acc[1][1]+=a.y*b.y; acc[1][2]+=a.y*b.z; acc[1][3]+=a.y*b.w;
                acc[2][0]+=a.z*b.x; acc[2][1]+=a.z*b.y; acc[2][2]+=a.z*b.z; acc[2][3]+=a.z*b.w;
                acc[3][0]+=a.w*b.x; acc[3][1]+=a.w*b.y; acc[3][2]+=a.w*b.z; acc[3][3]+=a.w*b.w;
            }
        }
    }
    #pragma unroll
    for (int im = 0; im < 4; ++im) {
        const int m = m0 + (tm << 2) + im;
        const float* wbm = WB + (size_t)m * NEXP;
        float wv[NEXP];
        #pragma unroll
        for (int e = 0; e < NEXP; ++e) wv[e] = wbm[e];
        #pragma unroll
        for (int in = 0; in < 4; ++in) {
            const int n = n0 + (tn << 2) + in;
            float bsum = 0.f;
            #pragma unroll
            for (int e = 0; e < NEXP; ++e) bsum += wv[e] * Bias[(size_t)e * Dout + n];
            float v = acc[im][in] + bsum;
            if (act) v = v > 0.f ? v : expm1f(v);
            acc[im][in] = v;
        }
        float4 o = make_float4(acc[im][0], acc[im][1], acc[im][2], acc[im][3]);
        *(float4*)(Y + (size_t)m * Dout + n0 + (tn << 2)) = o;
    }
}

extern "C" void kernel_launch(void* const* d_in, const int* in_sizes, int n_in,
                              void* d_out, int out_size, void* d_ws, size_t ws_size,
                              hipStream_t stream)
{
    (void)in_sizes; (void)n_in; (void)out_size;
    const float* wb = (const float*)d_in[0];
    const float* x  = (const float*)d_in[1];
    const float* W0 = (const float*)d_in[2];
    const float* B0 = (const float*)d_in[3];
    const float* W1 = (const float*)d_in[4];
    const float* B1 = (const float*)d_in[5];
    const float* W2 = (const float*)d_in[6];
    const float* B2 = (const float*)d_in[7];
    float* out = (float*)d_out;

    const size_t NW0 = (size_t)8*1024*512, NW1 = (size_t)8*1024*1024, NW2 = (size_t)8*512*1024;
    const size_t NX0 = (size_t)BATCH*512, NX1 = (size_t)BATCH*1024;
    const size_t need_main  = (NW0 + NW1 + NW2 + NX0 + 2 * NX1) * 2;          // ~44 MB
    const size_t need_split = need_main + 2 * (size_t)BATCH * 512 * 4;        // +8 MB

    if (ws_size >= need_main) {
        unsigned short* W0p = (unsigned short*)d_ws;
        unsigned short* W1p = W0p + NW0;
        unsigned short* W2p = W1p + NW1;
        unsigned short* x0p = W2p + NW2;
        unsigned short* x1p = x0p + NX0;
        unsigned short* x2p = x1p + NX1;
        pack32<<<2176, 256, 0, stream>>>(W0, W1, W2, x, W0p, W1p, W2p, x0p);
        // L0: K=512 (KBx=32), Dout=1024, ELU, packed out (next KBx=64)
        moe_gemm32<<<dim3(16, 32), 256, 0, stream>>>(x0p, W0p, B0, wb, x1p,
                                                     32, 0, 1024, 32, 64, 1, 1, 1);
        // L1: K=1024 (KBx=64), Dout=1024, ELU, packed out (next KBx=64)
        moe_gemm32<<<dim3(16, 32), 256, 0, stream>>>(x1p, W1p, B1, wb, x2p,
                                                     64, 0, 1024, 64, 64, 1, 1, 1);
        if (ws_size >= need_split) {
            float* p0 = (float*)(x2p + NX1);
            float* p1 = p0 + (size_t)BATCH * 512;
            moe_gemm32<<<dim3(8, 32), 256, 0, stream>>>(x2p, W2p, B2, wb, p0,
                                                        32, 0, 512, 64, 0, 0, 1, 0);
            moe_gemm32<<<dim3(8, 32), 256, 0, stream>>>(x2p, W2p, B2, wb, p1,
                                                        32, 32, 512, 64, 0, 0, 0, 0);
            reduce2<<<1024, 256, 0, stream>>>(p0, p1, out, BATCH * 512 / 4);
        } else {
            moe_gemm32<<<dim3(8, 32), 256, 0, stream>>>(x2p, W2p, B2, wb, out,
                                                        64, 0, 512, 64, 0, 0, 1, 0);
        }
    } else {
        float* x1 = (float*)d_ws;
        float* x2 = x1 + (size_t)BATCH * 1024;
        moe_layer_f32<<<dim3(1024/BNF, BATCH/BM), 256, 0, stream>>>(x,  W0, B0, wb, x1, 512,  1024, 1);
        moe_layer_f32<<<dim3(1024/BNF, BATCH/BM), 256, 0, stream>>>(x1, W1, B1, wb, x2, 1024, 1024, 1);
        moe_layer_f32<<<dim3(512/BNF,  BATCH/BM), 256, 0, stream>>>(x2, W2, B2, wb, out, 1024, 512,  0);
    }
}